// Round 5
// baseline (450.127 us; speedup 1.0000x reference)
//
#include <hip/hip_runtime.h>

// ---------------- static graph constants (Traffic4cast 495x436 grid) -------
#define NN 215820          // 495*436 nodes
#define NPOOL 54064        // 248*218 pooled nodes
#define KN 53846           // kept pooled edges north/south  247*218
#define KE 53816           // kept pooled edges east/west    248*217

// output layout offsets (in floats)
static constexpr size_t OFF_POS = (size_t)NPOOL * 128;
static constexpr size_t OFF_EIN = OFF_POS + (size_t)NPOOL * 2;
static constexpr size_t OFF_EIE = OFF_EIN + (size_t)KN * 2;
static constexpr size_t OFF_EIS = OFF_EIE + (size_t)KE * 2;
static constexpr size_t OFF_EIW = OFF_EIS + (size_t)KN * 2;
static constexpr size_t OFF_EFN = OFF_EIW + (size_t)KE * 2;
static constexpr size_t OFF_EFE = OFF_EFN + (size_t)KN * 32;
static constexpr size_t OFF_EFS = OFF_EFE + (size_t)KE * 32;
static constexpr size_t OFF_EFW = OFF_EFS + (size_t)KN * 32;

typedef __attribute__((ext_vector_type(8))) short  short8v;
typedef __attribute__((ext_vector_type(4))) float  floatx4;

// W_node transposed + split into bf16 hi/lo planes: [col 0..127][k 0..255]
__device__ __align__(16) unsigned short g_wn_h[128 * 256];
__device__ __align__(16) unsigned short g_wn_l[128 * 256];
// W_emb transposed + split: [col = q*32+u (0..127)][k 0..127]
__device__ __align__(16) unsigned short g_we_h[128 * 128];
__device__ __align__(16) unsigned short g_we_l[128 * 128];
// W_edge transposed + split: [q*32+col (0..127)][k 0..95]
__device__ __align__(16) unsigned short g_wd_h[128 * 96];
__device__ __align__(16) unsigned short g_wd_l[128 * 96];

// split fp32 -> truncated bf16 hi + bf16(residual) lo; combined rel err ~2^-16
__device__ __forceinline__ void bf16split(float x, unsigned short& h,
                                          unsigned short& l) {
  const unsigned int u = __float_as_uint(x);
  h = (unsigned short)(u >> 16);
  const float hf = __uint_as_float(u & 0xffff0000u);
  l = (unsigned short)(__float_as_uint(x - hf) >> 16);
}

// ---------------------------------------------------------------------------
// Kernel A (MFMA): xq[q][n][u] = relu(x @ W_emb[q]) for all 4 q at once.
// T14 prefetch: next chunk's global loads issue during current chunk's MFMA.
__global__ __launch_bounds__(256, 4) void k_xq(const float* __restrict__ x,
                                               float* __restrict__ xq) {
  __shared__ __align__(16) short As_h[128 * 32], As_l[128 * 32];
  __shared__ __align__(16) short Bs_h[128 * 32], Bs_l[128 * 32];
  const int t  = threadIdx.x;
  const int n0 = blockIdx.x * 128;
  const int srow = t >> 1, q0 = t & 1;
  int sn = n0 + srow; if (sn >= NN) sn = NN - 1;
  const float* srcx = x + (size_t)sn * 128;
  const int w = t >> 6, lane = t & 63;
  const int lr = lane & 15, lg = lane >> 4;

  floatx4 acc[2][8];
#pragma unroll
  for (int mi = 0; mi < 2; ++mi)
#pragma unroll
    for (int ni = 0; ni < 8; ++ni) acc[mi][ni] = (floatx4){0.f, 0.f, 0.f, 0.f};

  // prefetch chunk 0 A data to regs
  floatx4 nv[2][2];
#pragma unroll
  for (int cc = 0; cc < 2; ++cc) {
    nv[cc][0] = *(const floatx4*)(srcx + q0 * 8 + cc * 16);
    nv[cc][1] = *(const floatx4*)(srcx + q0 * 8 + cc * 16 + 4);
  }

  for (int ks = 0; ks < 4; ++ks) {
    __syncthreads();
#pragma unroll
    for (int cc = 0; cc < 2; ++cc) {
      const int q = q0 + 2 * cc;
      short8v hv, lv;
#pragma unroll
      for (int j = 0; j < 4; ++j) {
        unsigned short h, l;
        bf16split(nv[cc][0][j], h, l); hv[j] = (short)h; lv[j] = (short)l;
        bf16split(nv[cc][1][j], h, l); hv[4 + j] = (short)h; lv[4 + j] = (short)l;
      }
      const int off = srow * 64 + ((q * 16) ^ ((srow & 3) << 4));
      *(short8v*)((char*)As_h + off) = hv;
      *(short8v*)((char*)As_l + off) = lv;
      const size_t wb = (size_t)srow * 128 + ks * 32 + q * 8;
      *(short8v*)((char*)Bs_h + off) = *(const short8v*)(g_we_h + wb);
      *(short8v*)((char*)Bs_l + off) = *(const short8v*)(g_we_l + wb);
    }
    __syncthreads();
    if (ks < 3) {   // issue next chunk's loads; latency hides under MFMA
#pragma unroll
      for (int cc = 0; cc < 2; ++cc) {
        nv[cc][0] = *(const floatx4*)(srcx + (ks + 1) * 32 + q0 * 8 + cc * 16);
        nv[cc][1] = *(const floatx4*)(srcx + (ks + 1) * 32 + q0 * 8 + cc * 16 + 4);
      }
    }
    short8v ah[2], al[2];
#pragma unroll
    for (int mi = 0; mi < 2; ++mi) {
      const int row = (mi ? 64 : 0) + 16 * w + lr;
      const int off = row * 64 + ((lg * 16) ^ ((row & 3) << 4));
      ah[mi] = *(const short8v*)((const char*)As_h + off);
      al[mi] = *(const short8v*)((const char*)As_l + off);
    }
#pragma unroll
    for (int ni = 0; ni < 8; ++ni) {
      const int col = 16 * ni + lr;
      const int off = col * 64 + ((lg * 16) ^ ((col & 3) << 4));
      const short8v bh = *(const short8v*)((const char*)Bs_h + off);
      const short8v bl = *(const short8v*)((const char*)Bs_l + off);
#pragma unroll
      for (int mi = 0; mi < 2; ++mi) {
        acc[mi][ni] = __builtin_amdgcn_mfma_f32_16x16x32_bf16(ah[mi], bh, acc[mi][ni], 0, 0, 0);
        acc[mi][ni] = __builtin_amdgcn_mfma_f32_16x16x32_bf16(ah[mi], bl, acc[mi][ni], 0, 0, 0);
        acc[mi][ni] = __builtin_amdgcn_mfma_f32_16x16x32_bf16(al[mi], bh, acc[mi][ni], 0, 0, 0);
      }
    }
  }
#pragma unroll
  for (int ni = 0; ni < 8; ++ni) {
    const int col = 16 * ni + lr;
    const int qq = col >> 5, u = col & 31;
#pragma unroll
    for (int mi = 0; mi < 2; ++mi) {
      const int nb = n0 + (mi ? 64 : 0) + 16 * w + 4 * lg;
#pragma unroll
      for (int r = 0; r < 4; ++r) {
        const int n = nb + r;
        if (n < NN)
          xq[((size_t)qq * NN + n) * 32 + u] = fmaxf(acc[mi][ni][r], 0.f);
      }
    }
  }
}

// ---------------------------------------------------------------------------
// Kernel C (MFMA): x2 = relu([x|agg] @ W_node) + in-register 2x2 pooled max.
// T14 prefetch of next A chunk (x / agg).
__global__ __launch_bounds__(256, 4) void k_node(const float* __restrict__ x,
                                                 const float* __restrict__ agg,
                                                 float* __restrict__ out) {
  __shared__ short As_h[128 * 32], As_l[128 * 32];
  __shared__ short Bs_h[128 * 32], Bs_l[128 * 32];
  const int t   = threadIdx.x;
  const int pr  = blockIdx.y;          // pooled row 0..247
  const int pc0 = blockIdx.x * 32;     // pooled col base 0..192

  const int srow = t >> 1, q0 = t & 1;
  int ra = (srow < 64) ? 2 * pr : 2 * pr + 1; if (ra > 494) ra = 494;
  int ca = 2 * pc0 + (srow & 63);          if (ca > 435) ca = 435;
  const size_t snode = (size_t)ra * 436 + ca;
  const float* xb   = x   + snode * 128;
  const float* ab   = agg + snode * 128;

  const int w = t >> 6, lane = t & 63;
  const int lr = lane & 15, lg = lane >> 4;

  floatx4 acc[2][8];
#pragma unroll
  for (int mi = 0; mi < 2; ++mi)
#pragma unroll
    for (int ni = 0; ni < 8; ++ni) acc[mi][ni] = (floatx4){0.f, 0.f, 0.f, 0.f};

  floatx4 nv[2][2];
#pragma unroll
  for (int cc = 0; cc < 2; ++cc) {
    nv[cc][0] = *(const floatx4*)(xb + q0 * 8 + cc * 16);
    nv[cc][1] = *(const floatx4*)(xb + q0 * 8 + cc * 16 + 4);
  }

  for (int ks = 0; ks < 8; ++ks) {
    __syncthreads();
#pragma unroll
    for (int cc = 0; cc < 2; ++cc) {
      const int q = q0 + 2 * cc;
      short8v hv, lv;
#pragma unroll
      for (int j = 0; j < 4; ++j) {
        unsigned short h, l;
        bf16split(nv[cc][0][j], h, l); hv[j] = (short)h; lv[j] = (short)l;
        bf16split(nv[cc][1][j], h, l); hv[4 + j] = (short)h; lv[4 + j] = (short)l;
      }
      const int off = srow * 64 + ((q * 16) ^ ((srow & 3) << 4));
      *(short8v*)((char*)As_h + off) = hv;
      *(short8v*)((char*)As_l + off) = lv;
      const size_t wb = (size_t)srow * 256 + ks * 32 + q * 8;
      *(short8v*)((char*)Bs_h + off) = *(const short8v*)(g_wn_h + wb);
      *(short8v*)((char*)Bs_l + off) = *(const short8v*)(g_wn_l + wb);
    }
    __syncthreads();
    if (ks < 7) {
      const int kn = ks + 1;
      const float* src = (kn < 4) ? (xb + kn * 32) : (ab + (kn - 4) * 32);
#pragma unroll
      for (int cc = 0; cc < 2; ++cc) {
        nv[cc][0] = *(const floatx4*)(src + q0 * 8 + cc * 16);
        nv[cc][1] = *(const floatx4*)(src + q0 * 8 + cc * 16 + 4);
      }
    }
    short8v ah[2], al[2];
#pragma unroll
    for (int mi = 0; mi < 2; ++mi) {
      const int row = (mi ? 64 : 0) + 16 * w + lr;
      const int off = row * 64 + ((lg * 16) ^ ((row & 3) << 4));
      ah[mi] = *(const short8v*)((const char*)As_h + off);
      al[mi] = *(const short8v*)((const char*)As_l + off);
    }
#pragma unroll
    for (int ni = 0; ni < 8; ++ni) {
      const int col = 16 * ni + lr;
      const int off = col * 64 + ((lg * 16) ^ ((col & 3) << 4));
      const short8v bh = *(const short8v*)((const char*)Bs_h + off);
      const short8v bl = *(const short8v*)((const char*)Bs_l + off);
#pragma unroll
      for (int mi = 0; mi < 2; ++mi) {
        acc[mi][ni] = __builtin_amdgcn_mfma_f32_16x16x32_bf16(ah[mi], bh, acc[mi][ni], 0, 0, 0);
        acc[mi][ni] = __builtin_amdgcn_mfma_f32_16x16x32_bf16(ah[mi], bl, acc[mi][ni], 0, 0, 0);
        acc[mi][ni] = __builtin_amdgcn_mfma_f32_16x16x32_bf16(al[mi], bh, acc[mi][ni], 0, 0, 0);
      }
    }
  }
#pragma unroll
  for (int ni = 0; ni < 8; ++ni) {
#pragma unroll
    for (int k = 0; k < 2; ++k) {
      float v = fmaxf(fmaxf(acc[0][ni][2 * k], acc[0][ni][2 * k + 1]),
                      fmaxf(acc[1][ni][2 * k], acc[1][ni][2 * k + 1]));
      v = fmaxf(v, 0.f);
      const int pc = pc0 + 8 * w + 2 * lg + k;
      if (pc < 218) out[((size_t)pr * 218 + pc) * 128 + 16 * ni + lr] = v;
    }
  }
}

// ---------------------------------------------------------------------------
// Kernel B (MFMA): edge MLP as [128 edges][96] @ [96][32] GEMM.
// Latency fix: ALL A-chunk loads (3 x 2 x float4-pair) issued at block start;
// B staged ONCE for full K=96 ([32 col][192 B], per-64B XOR swizzle).
__global__ __launch_bounds__(256, 4) void k_edge(
    const float* __restrict__ ef_n, const float* __restrict__ ef_e,
    const float* __restrict__ ef_s, const float* __restrict__ ef_w,
    const float* __restrict__ xq, float* __restrict__ agg,
    float* __restrict__ out) {
  __shared__ __align__(16) short As_h[128 * 32], As_l[128 * 32];
  __shared__ __align__(16) short Bs_h[32 * 96],  Bs_l[32 * 96];
  const int t = threadIdx.x;
  int b = blockIdx.x;

  // ---- decode tile: N 494x4 | S 494x4 | E 248x7 | W 248x7
  int q, row = 0, pr = 0, c0;
  const float* ef; float* efb;
  if (b < 1976)        { q = 0; ef = ef_n; efb = out + OFF_EFN;
                         row = b >> 2; c0 = (b & 3) * 128; if (c0 > 308) c0 = 308; }
  else if (b < 3952)   { b -= 1976; q = 2; ef = ef_s; efb = out + OFF_EFS;
                         row = b >> 2; c0 = (b & 3) * 128; if (c0 > 308) c0 = 308; }
  else if (b < 5688)   { b -= 3952; q = 1; ef = ef_e; efb = out + OFF_EFE;
                         pr = b / 7;  c0 = (b - pr * 7) * 64; if (c0 > 371) c0 = 371; }
  else                 { b -= 5688; q = 3; ef = ef_w; efb = out + OFF_EFW;
                         pr = b / 7;  c0 = (b - pr * 7) * 64; if (c0 > 371) c0 = 371; }
  const float* xqq = xq + (size_t)q * NN * 32;

  // ---- per-thread staging bases for the 3 K-chunks
  const int srow = t >> 1, q0 = t & 1;
  const float *base0, *base1, *base2;
  if (q == 0) {                       // north: erow=row; src=e+436, dst=e
    const int e = row * 436 + c0 + srow;
    base0 = ef  + (size_t)e * 32;
    base1 = xqq + (size_t)(e + 436) * 32;
    base2 = xqq + (size_t)e * 32;
  } else if (q == 2) {                // south: src=e, dst=e+436
    const int e = row * 436 + c0 + srow;
    base0 = ef  + (size_t)e * 32;
    base1 = xqq + (size_t)e * 32;
    base2 = xqq + (size_t)(e + 436) * 32;
  } else {
    int r = 2 * pr + (srow >> 6); if (r > 494) r = 494;
    const int cc = c0 + (srow & 63);
    if (q == 1) {                     // east: src=r*436+c, dst=src+1
      base0 = ef  + ((size_t)r * 435 + cc) * 32;
      base1 = xqq + ((size_t)r * 436 + cc) * 32;
      base2 = base1 + 32;
    } else {                          // west: cm=cc, c=cc+1, dst=src-1
      base0 = ef  + ((size_t)r * 435 + cc) * 32;
      base1 = xqq + ((size_t)r * 436 + cc + 1) * 32;
      base2 = base1 - 32;
    }
  }

  // ---- prefetch ALL A data (one latency exposure per block)
  floatx4 pv[3][2][2];
#pragma unroll
  for (int kc = 0; kc < 3; ++kc) {
    const float* src = (kc == 0) ? base0 : (kc == 1) ? base1 : base2;
#pragma unroll
    for (int cc = 0; cc < 2; ++cc) {
      pv[kc][cc][0] = *(const floatx4*)(src + (q0 + 2 * cc) * 8);
      pv[kc][cc][1] = *(const floatx4*)(src + (q0 + 2 * cc) * 8 + 4);
    }
  }
  // ---- stage B once: 768 16B-slabs across hi+lo planes
#pragma unroll
  for (int r = 0; r < 3; ++r) {
    const int g = r * 256 + t;
    const bool lo = g >= 384;
    const int f = lo ? g - 384 : g;
    const int col = f / 12, rem = f - col * 12, kc = rem >> 2, ch = rem & 3;
    const unsigned short* sp = (lo ? g_wd_l : g_wd_h) +
                               (size_t)(q * 32 + col) * 96 + kc * 32 + ch * 8;
    short* dp = lo ? Bs_l : Bs_h;
    const int off = col * 192 + kc * 64 + ((ch * 16) ^ ((col & 3) << 4));
    *(short8v*)((char*)dp + off) = *(const short8v*)sp;
  }

  const int w = t >> 6, lane = t & 63;
  const int lr = lane & 15, lg = lane >> 4;

  floatx4 acc[2][2];
#pragma unroll
  for (int mi = 0; mi < 2; ++mi)
#pragma unroll
    for (int ni = 0; ni < 2; ++ni) acc[mi][ni] = (floatx4){0.f, 0.f, 0.f, 0.f};

#pragma unroll
  for (int kc = 0; kc < 3; ++kc) {
    __syncthreads();                  // WAR on As; (kc=0: orders B stage too)
#pragma unroll
    for (int cc = 0; cc < 2; ++cc) {
      const int qch = q0 + 2 * cc;
      short8v hv, lv;
#pragma unroll
      for (int j = 0; j < 4; ++j) {
        unsigned short h, l;
        bf16split(pv[kc][cc][0][j], h, l); hv[j] = (short)h; lv[j] = (short)l;
        bf16split(pv[kc][cc][1][j], h, l); hv[4 + j] = (short)h; lv[4 + j] = (short)l;
      }
      const int off = srow * 64 + ((qch * 16) ^ ((srow & 3) << 4));
      *(short8v*)((char*)As_h + off) = hv;
      *(short8v*)((char*)As_l + off) = lv;
    }
    __syncthreads();
    short8v ah[2], al[2], bh[2], bl[2];
#pragma unroll
    for (int mi = 0; mi < 2; ++mi) {
      const int rowm = 64 * mi + 16 * w + lr;
      const int off = rowm * 64 + ((lg * 16) ^ ((rowm & 3) << 4));
      ah[mi] = *(const short8v*)((const char*)As_h + off);
      al[mi] = *(const short8v*)((const char*)As_l + off);
    }
#pragma unroll
    for (int ni = 0; ni < 2; ++ni) {
      const int col = 16 * ni + lr;
      const int off = col * 192 + kc * 64 + ((lg * 16) ^ ((col & 3) << 4));
      bh[ni] = *(const short8v*)((const char*)Bs_h + off);
      bl[ni] = *(const short8v*)((const char*)Bs_l + off);
    }
#pragma unroll
    for (int ni = 0; ni < 2; ++ni)
#pragma unroll
      for (int mi = 0; mi < 2; ++mi) {
        acc[mi][ni] = __builtin_amdgcn_mfma_f32_16x16x32_bf16(ah[mi], bh[ni], acc[mi][ni], 0, 0, 0);
        acc[mi][ni] = __builtin_amdgcn_mfma_f32_16x16x32_bf16(ah[mi], bl[ni], acc[mi][ni], 0, 0, 0);
        acc[mi][ni] = __builtin_amdgcn_mfma_f32_16x16x32_bf16(al[mi], bh[ni], acc[mi][ni], 0, 0, 0);
      }
  }

  // ---- epilogue: relu; agg scatter; pooled-max efeat
  float vv[2][2][4];
#pragma unroll
  for (int mi = 0; mi < 2; ++mi)
#pragma unroll
    for (int ni = 0; ni < 2; ++ni)
#pragma unroll
      for (int r = 0; r < 4; ++r) vv[mi][ni][r] = fmaxf(acc[mi][ni][r], 0.f);

#pragma unroll
  for (int ni = 0; ni < 2; ++ni) {
    const int colo = q * 32 + 16 * ni + lr;
#pragma unroll
    for (int mi = 0; mi < 2; ++mi) {
      size_t dstb;
      if (q == 0)      dstb = (size_t)row * 436 + c0 + 64 * mi + 16 * w + 4 * lg;
      else if (q == 2) dstb = (size_t)(row + 1) * 436 + c0 + 64 * mi + 16 * w + 4 * lg;
      else {
        int r2 = 2 * pr + mi; if (r2 > 494) r2 = 494;
        dstb = (size_t)r2 * 436 + c0 + 16 * w + 4 * lg + (q == 1 ? 1 : 0);
      }
#pragma unroll
      for (int r = 0; r < 4; ++r)
        agg[(dstb + r) * 128 + colo] = vv[mi][ni][r] * 0.25f;
    }
  }

  if (q == 0 || q == 2) {
    if (row & 1) {                    // kept rows: north erow odd, south r odd
      const int krow = row >> 1;
#pragma unroll
      for (int ni = 0; ni < 2; ++ni)
#pragma unroll
        for (int mi = 0; mi < 2; ++mi)
#pragma unroll
          for (int k = 0; k < 2; ++k) {
            const int c = c0 + 64 * mi + 16 * w + 4 * lg + 2 * k;
            const int kidx = krow * 218 + (c >> 1);
            const float val = fmaxf(vv[mi][ni][2 * k], vv[mi][ni][2 * k + 1]);
            efb[(size_t)kidx * 32 + 16 * ni + lr] = val;
          }
    }
  } else {
#pragma unroll
    for (int ni = 0; ni < 2; ++ni)
#pragma unroll
      for (int r = 0; r < 4; ++r) {
        const int jj = 16 * w + 4 * lg + r;
        const int c = c0 + jj + (q == 3 ? 1 : 0);
        const bool kept = (q == 1) ? ((c & 1) == 1) : ((c & 1) == 0);
        if (kept) {
          const int kidx = pr * 217 + (c >> 1) - (q == 3 ? 1 : 0);
          const float val = fmaxf(vv[0][ni][r], vv[1][ni][r]);
          efb[(size_t)kidx * 32 + 16 * ni + lr] = val;
        }
      }
  }
}

// ---------------------------------------------------------------------------
// Kernel D: zero agg boundary strips + closed-form new_pos + pooled edge
// indices + W_node / W_emb / W_edge transpose-split prep.
__global__ __launch_bounds__(256) void k_misc(float* __restrict__ out,
                                              float* __restrict__ agg,
                                              const float* __restrict__ W_node,
                                              const float* __restrict__ W_emb,
                                              const float* __restrict__ W_edge) {
  int u = blockIdx.x * 256 + threadIdx.x;
  if (u < 436 * 32) {  // north: dst row 494 missing
    agg[((size_t)494 * 436 + (u >> 5)) * 128 + (u & 31)] = 0.f; return;
  }
  u -= 436 * 32;
  if (u < 495 * 32) {  // east: dst col 0 missing
    agg[(size_t)(u >> 5) * 436 * 128 + 32 + (u & 31)] = 0.f; return;
  }
  u -= 495 * 32;
  if (u < 436 * 32) {  // south: dst row 0 missing
    agg[(size_t)(u >> 5) * 128 + 64 + (u & 31)] = 0.f; return;
  }
  u -= 436 * 32;
  if (u < 495 * 32) {  // west: dst col 435 missing
    agg[((size_t)(u >> 5) * 436 + 435) * 128 + 96 + (u & 31)] = 0.f; return;
  }
  u -= 495 * 32;
  if (u < NPOOL * 2) {
    const int p  = u >> 1;
    const int pr = p / 218, pc = p - pr * 218;
    out[OFF_POS + u] = (float)((u & 1) ? pc : pr); return;
  }
  u -= NPOOL * 2;
  if (u < KN * 2) {   // north
    const int e  = u >> 1;
    const int kr = e / 218 + 1, pc = e - (kr - 1) * 218;
    const int s  = kr * 218 + pc;
    out[OFF_EIN + u] = (float)((u & 1) ? (s - 218) : s); return;
  }
  u -= KN * 2;
  if (u < KE * 2) {   // east
    const int e  = u >> 1;
    const int pr = e / 217, jj = e - pr * 217;
    const int s  = pr * 218 + jj;
    out[OFF_EIE + u] = (float)((u & 1) ? (s + 1) : s); return;
  }
  u -= KE * 2;
  if (u < KN * 2) {   // south
    const int e  = u >> 1;
    const int k  = e / 218, pc = e - k * 218;
    const int s  = k * 218 + pc;
    out[OFF_EIS + u] = (float)((u & 1) ? (s + 218) : s); return;
  }
  u -= KN * 2;
  if (u < KE * 2) {   // west
    const int e  = u >> 1;
    const int pr = e / 217, jj = e - pr * 217;
    const int s  = pr * 218 + jj + 1;
    out[OFF_EIW + u] = (float)((u & 1) ? (s - 1) : s); return;
  }
  u -= KE * 2;
  if (u < 256 * 128) { // W_node [k][c] -> transposed bf16 hi/lo planes [c][k]
    const int k = u >> 7, c = u & 127;
    unsigned short h, l;
    bf16split(W_node[u], h, l);
    g_wn_h[(size_t)c * 256 + k] = h;
    g_wn_l[(size_t)c * 256 + k] = l;
    return;
  }
  u -= 256 * 128;
  if (u < 4 * 128 * 32) { // W_emb [q][k][uu] -> planes [(q*32+uu)][k]
    const int q = u >> 12, k = (u >> 5) & 127, uu = u & 31;
    unsigned short h, l;
    bf16split(W_emb[u], h, l);
    g_we_h[(size_t)(q * 32 + uu) * 128 + k] = h;
    g_we_l[(size_t)(q * 32 + uu) * 128 + k] = l;
    return;
  }
  u -= 4 * 128 * 32;
  if (u < 4 * 96 * 32) { // W_edge [q][k][col] -> planes [(q*32+col)][k 0..95]
    const int q = u / 3072, rem = u - q * 3072;
    const int k = rem >> 5, col = rem & 31;
    unsigned short h, l;
    bf16split(W_edge[u], h, l);
    g_wd_h[(size_t)(q * 32 + col) * 96 + k] = h;
    g_wd_l[(size_t)(q * 32 + col) * 96 + k] = l;
  }
}

// ---------------------------------------------------------------------------
extern "C" void kernel_launch(void* const* d_in, const int* in_sizes, int n_in,
                              void* d_out, int out_size, void* d_ws, size_t ws_size,
                              hipStream_t stream) {
  const float* x      = (const float*)d_in[0];
  const float* ef_n   = (const float*)d_in[6];
  const float* ef_e   = (const float*)d_in[7];
  const float* ef_s   = (const float*)d_in[8];
  const float* ef_w   = (const float*)d_in[9];
  const float* W_emb  = (const float*)d_in[10];
  const float* W_edge = (const float*)d_in[11];
  const float* W_node = (const float*)d_in[12];
  float* out = (float*)d_out;

  float* xq  = (float*)d_ws;                 // [4][NN][32]
  float* agg = xq + (size_t)NN * 128;        // [NN][128]

  const int misc_total = (436 + 495 + 436 + 495) * 32 + NPOOL * 2 +
                         2 * (KN * 2 + KE * 2) + 256 * 128 + 4 * 128 * 32 +
                         4 * 96 * 32;
  k_misc<<<dim3((misc_total + 255) / 256), 256, 0, stream>>>(out, agg, W_node,
                                                             W_emb, W_edge);
  k_xq  <<<dim3((NN + 127) / 128), 256, 0, stream>>>(x, xq);
  k_edge<<<dim3(7424), 256, 0, stream>>>(ef_n, ef_e, ef_s, ef_w,
                                         xq, agg, out);
  k_node<<<dim3(7, 248), 256, 0, stream>>>(x, agg, out);
}

// Round 6
// 438.946 us; speedup vs baseline: 1.0255x; 1.0255x over previous
//
#include <hip/hip_runtime.h>

// ---------------- static graph constants (Traffic4cast 495x436 grid) -------
#define NN 215820          // 495*436 nodes
#define NPOOL 54064        // 248*218 pooled nodes
#define KN 53846           // kept pooled edges north/south  247*218
#define KE 53816           // kept pooled edges east/west    248*217

// output layout offsets (in floats)
static constexpr size_t OFF_POS = (size_t)NPOOL * 128;
static constexpr size_t OFF_EIN = OFF_POS + (size_t)NPOOL * 2;
static constexpr size_t OFF_EIE = OFF_EIN + (size_t)KN * 2;
static constexpr size_t OFF_EIS = OFF_EIE + (size_t)KE * 2;
static constexpr size_t OFF_EIW = OFF_EIS + (size_t)KN * 2;
static constexpr size_t OFF_EFN = OFF_EIW + (size_t)KE * 2;
static constexpr size_t OFF_EFE = OFF_EFN + (size_t)KN * 32;
static constexpr size_t OFF_EFS = OFF_EFE + (size_t)KE * 32;
static constexpr size_t OFF_EFW = OFF_EFS + (size_t)KN * 32;

typedef __attribute__((ext_vector_type(8))) short  short8v;
typedef __attribute__((ext_vector_type(4))) float  floatx4;

// W_node transposed + split into bf16 hi/lo planes: [col 0..127][k 0..255]
__device__ __align__(16) unsigned short g_wn_h[128 * 256];
__device__ __align__(16) unsigned short g_wn_l[128 * 256];
// W_emb transposed + split: [col = q*32+u (0..127)][k 0..127]
__device__ __align__(16) unsigned short g_we_h[128 * 128];
__device__ __align__(16) unsigned short g_we_l[128 * 128];
// W_edge transposed + split: [q*32+col (0..127)][k 0..95]
__device__ __align__(16) unsigned short g_wd_h[128 * 96];
__device__ __align__(16) unsigned short g_wd_l[128 * 96];

// split fp32 -> truncated bf16 hi + bf16(residual) lo; combined rel err ~2^-16
__device__ __forceinline__ void bf16split(float x, unsigned short& h,
                                          unsigned short& l) {
  const unsigned int u = __float_as_uint(x);
  h = (unsigned short)(u >> 16);
  const float hf = __uint_as_float(u & 0xffff0000u);
  l = (unsigned short)(__float_as_uint(x - hf) >> 16);
}

// LDS-only barrier: does NOT drain vmcnt, so register-destined global loads
// stay in flight across it (the __syncthreads drain was the round-5 stall).
// lgkmcnt(0) orders our ds_writes before the barrier; sched_barrier(0) stops
// the scheduler hoisting the following ds_reads above it (rule #18).
__device__ __forceinline__ void bar_lds() {
  asm volatile("s_waitcnt lgkmcnt(0)" ::: "memory");
  __builtin_amdgcn_s_barrier();
  __builtin_amdgcn_sched_barrier(0);
}

// ---------------------------------------------------------------------------
// Kernel A (MFMA): xq[q][n][u] = relu(x @ W_emb[q]) for all 4 q at once.
// Next-chunk A prefetch rides across the lgkmcnt-only barriers.
__global__ __launch_bounds__(256, 4) void k_xq(const float* __restrict__ x,
                                               float* __restrict__ xq) {
  __shared__ __align__(16) short As_h[128 * 32], As_l[128 * 32];
  __shared__ __align__(16) short Bs_h[128 * 32], Bs_l[128 * 32];
  const int t  = threadIdx.x;
  const int n0 = blockIdx.x * 128;
  const int srow = t >> 1, q0 = t & 1;
  int sn = n0 + srow; if (sn >= NN) sn = NN - 1;
  const float* srcx = x + (size_t)sn * 128;
  const int w = t >> 6, lane = t & 63;
  const int lr = lane & 15, lg = lane >> 4;

  floatx4 acc[2][8];
#pragma unroll
  for (int mi = 0; mi < 2; ++mi)
#pragma unroll
    for (int ni = 0; ni < 8; ++ni) acc[mi][ni] = (floatx4){0.f, 0.f, 0.f, 0.f};

  // prefetch chunk 0 A data to regs
  floatx4 nv[2][2];
#pragma unroll
  for (int cc = 0; cc < 2; ++cc) {
    nv[cc][0] = *(const floatx4*)(srcx + q0 * 8 + cc * 16);
    nv[cc][1] = *(const floatx4*)(srcx + q0 * 8 + cc * 16 + 4);
  }

  for (int ks = 0; ks < 4; ++ks) {
    bar_lds();
#pragma unroll
    for (int cc = 0; cc < 2; ++cc) {
      const int q = q0 + 2 * cc;
      short8v hv, lv;
#pragma unroll
      for (int j = 0; j < 4; ++j) {
        unsigned short h, l;
        bf16split(nv[cc][0][j], h, l); hv[j] = (short)h; lv[j] = (short)l;
        bf16split(nv[cc][1][j], h, l); hv[4 + j] = (short)h; lv[4 + j] = (short)l;
      }
      const int off = srow * 64 + ((q * 16) ^ ((srow & 3) << 4));
      *(short8v*)((char*)As_h + off) = hv;
      *(short8v*)((char*)As_l + off) = lv;
      const size_t wb = (size_t)srow * 128 + ks * 32 + q * 8;
      *(short8v*)((char*)Bs_h + off) = *(const short8v*)(g_we_h + wb);
      *(short8v*)((char*)Bs_l + off) = *(const short8v*)(g_we_l + wb);
    }
    bar_lds();
    if (ks < 3) {   // next chunk's loads: in flight across the next barrier
#pragma unroll
      for (int cc = 0; cc < 2; ++cc) {
        nv[cc][0] = *(const floatx4*)(srcx + (ks + 1) * 32 + q0 * 8 + cc * 16);
        nv[cc][1] = *(const floatx4*)(srcx + (ks + 1) * 32 + q0 * 8 + cc * 16 + 4);
      }
    }
    short8v ah[2], al[2];
#pragma unroll
    for (int mi = 0; mi < 2; ++mi) {
      const int row = (mi ? 64 : 0) + 16 * w + lr;
      const int off = row * 64 + ((lg * 16) ^ ((row & 3) << 4));
      ah[mi] = *(const short8v*)((const char*)As_h + off);
      al[mi] = *(const short8v*)((const char*)As_l + off);
    }
#pragma unroll
    for (int ni = 0; ni < 8; ++ni) {
      const int col = 16 * ni + lr;
      const int off = col * 64 + ((lg * 16) ^ ((col & 3) << 4));
      const short8v bh = *(const short8v*)((const char*)Bs_h + off);
      const short8v bl = *(const short8v*)((const char*)Bs_l + off);
#pragma unroll
      for (int mi = 0; mi < 2; ++mi) {
        acc[mi][ni] = __builtin_amdgcn_mfma_f32_16x16x32_bf16(ah[mi], bh, acc[mi][ni], 0, 0, 0);
        acc[mi][ni] = __builtin_amdgcn_mfma_f32_16x16x32_bf16(ah[mi], bl, acc[mi][ni], 0, 0, 0);
        acc[mi][ni] = __builtin_amdgcn_mfma_f32_16x16x32_bf16(al[mi], bh, acc[mi][ni], 0, 0, 0);
      }
    }
  }
#pragma unroll
  for (int ni = 0; ni < 8; ++ni) {
    const int col = 16 * ni + lr;
    const int qq = col >> 5, u = col & 31;
#pragma unroll
    for (int mi = 0; mi < 2; ++mi) {
      const int nb = n0 + (mi ? 64 : 0) + 16 * w + 4 * lg;
#pragma unroll
      for (int r = 0; r < 4; ++r) {
        const int n = nb + r;
        if (n < NN)
          xq[((size_t)qq * NN + n) * 32 + u] = fmaxf(acc[mi][ni][r], 0.f);
      }
    }
  }
}

// ---------------------------------------------------------------------------
// Kernel C (MFMA): x2 = relu([x|agg] @ W_node) + in-register 2x2 pooled max.
// Next-chunk A prefetch + lgkmcnt-only barriers.
__global__ __launch_bounds__(256, 4) void k_node(const float* __restrict__ x,
                                                 const float* __restrict__ agg,
                                                 float* __restrict__ out) {
  __shared__ short As_h[128 * 32], As_l[128 * 32];
  __shared__ short Bs_h[128 * 32], Bs_l[128 * 32];
  const int t   = threadIdx.x;
  const int pr  = blockIdx.y;          // pooled row 0..247
  const int pc0 = blockIdx.x * 32;     // pooled col base 0..192

  const int srow = t >> 1, q0 = t & 1;
  int ra = (srow < 64) ? 2 * pr : 2 * pr + 1; if (ra > 494) ra = 494;
  int ca = 2 * pc0 + (srow & 63);          if (ca > 435) ca = 435;
  const size_t snode = (size_t)ra * 436 + ca;
  const float* xb   = x   + snode * 128;
  const float* ab   = agg + snode * 128;

  const int w = t >> 6, lane = t & 63;
  const int lr = lane & 15, lg = lane >> 4;

  floatx4 acc[2][8];
#pragma unroll
  for (int mi = 0; mi < 2; ++mi)
#pragma unroll
    for (int ni = 0; ni < 8; ++ni) acc[mi][ni] = (floatx4){0.f, 0.f, 0.f, 0.f};

  floatx4 nv[2][2];
#pragma unroll
  for (int cc = 0; cc < 2; ++cc) {
    nv[cc][0] = *(const floatx4*)(xb + q0 * 8 + cc * 16);
    nv[cc][1] = *(const floatx4*)(xb + q0 * 8 + cc * 16 + 4);
  }

  for (int ks = 0; ks < 8; ++ks) {
    bar_lds();
#pragma unroll
    for (int cc = 0; cc < 2; ++cc) {
      const int q = q0 + 2 * cc;
      short8v hv, lv;
#pragma unroll
      for (int j = 0; j < 4; ++j) {
        unsigned short h, l;
        bf16split(nv[cc][0][j], h, l); hv[j] = (short)h; lv[j] = (short)l;
        bf16split(nv[cc][1][j], h, l); hv[4 + j] = (short)h; lv[4 + j] = (short)l;
      }
      const int off = srow * 64 + ((q * 16) ^ ((srow & 3) << 4));
      *(short8v*)((char*)As_h + off) = hv;
      *(short8v*)((char*)As_l + off) = lv;
      const size_t wb = (size_t)srow * 256 + ks * 32 + q * 8;
      *(short8v*)((char*)Bs_h + off) = *(const short8v*)(g_wn_h + wb);
      *(short8v*)((char*)Bs_l + off) = *(const short8v*)(g_wn_l + wb);
    }
    bar_lds();
    if (ks < 7) {
      const int kn = ks + 1;
      const float* src = (kn < 4) ? (xb + kn * 32) : (ab + (kn - 4) * 32);
#pragma unroll
      for (int cc = 0; cc < 2; ++cc) {
        nv[cc][0] = *(const floatx4*)(src + q0 * 8 + cc * 16);
        nv[cc][1] = *(const floatx4*)(src + q0 * 8 + cc * 16 + 4);
      }
    }
    short8v ah[2], al[2];
#pragma unroll
    for (int mi = 0; mi < 2; ++mi) {
      const int row = (mi ? 64 : 0) + 16 * w + lr;
      const int off = row * 64 + ((lg * 16) ^ ((row & 3) << 4));
      ah[mi] = *(const short8v*)((const char*)As_h + off);
      al[mi] = *(const short8v*)((const char*)As_l + off);
    }
#pragma unroll
    for (int ni = 0; ni < 8; ++ni) {
      const int col = 16 * ni + lr;
      const int off = col * 64 + ((lg * 16) ^ ((col & 3) << 4));
      const short8v bh = *(const short8v*)((const char*)Bs_h + off);
      const short8v bl = *(const short8v*)((const char*)Bs_l + off);
#pragma unroll
      for (int mi = 0; mi < 2; ++mi) {
        acc[mi][ni] = __builtin_amdgcn_mfma_f32_16x16x32_bf16(ah[mi], bh, acc[mi][ni], 0, 0, 0);
        acc[mi][ni] = __builtin_amdgcn_mfma_f32_16x16x32_bf16(ah[mi], bl, acc[mi][ni], 0, 0, 0);
        acc[mi][ni] = __builtin_amdgcn_mfma_f32_16x16x32_bf16(al[mi], bh, acc[mi][ni], 0, 0, 0);
      }
    }
  }
#pragma unroll
  for (int ni = 0; ni < 8; ++ni) {
#pragma unroll
    for (int k = 0; k < 2; ++k) {
      float v = fmaxf(fmaxf(acc[0][ni][2 * k], acc[0][ni][2 * k + 1]),
                      fmaxf(acc[1][ni][2 * k], acc[1][ni][2 * k + 1]));
      v = fmaxf(v, 0.f);
      const int pc = pc0 + 8 * w + 2 * lg + k;
      if (pc < 218) out[((size_t)pr * 218 + pc) * 128 + 16 * ni + lr] = v;
    }
  }
}

// ---------------------------------------------------------------------------
// Kernel B (MFMA): edge MLP as [128 edges][96] @ [96][32] GEMM.
// ALL A-chunk loads issued at block start; with lgkmcnt-only barriers they
// now stay in flight across chunk boundaries (chunks 1-2 fully hidden).
__global__ __launch_bounds__(256, 4) void k_edge(
    const float* __restrict__ ef_n, const float* __restrict__ ef_e,
    const float* __restrict__ ef_s, const float* __restrict__ ef_w,
    const float* __restrict__ xq, float* __restrict__ agg,
    float* __restrict__ out) {
  __shared__ __align__(16) short As_h[128 * 32], As_l[128 * 32];
  __shared__ __align__(16) short Bs_h[32 * 96],  Bs_l[32 * 96];
  const int t = threadIdx.x;
  int b = blockIdx.x;

  // ---- decode tile: N 494x4 | S 494x4 | E 248x7 | W 248x7
  int q, row = 0, pr = 0, c0;
  const float* ef; float* efb;
  if (b < 1976)        { q = 0; ef = ef_n; efb = out + OFF_EFN;
                         row = b >> 2; c0 = (b & 3) * 128; if (c0 > 308) c0 = 308; }
  else if (b < 3952)   { b -= 1976; q = 2; ef = ef_s; efb = out + OFF_EFS;
                         row = b >> 2; c0 = (b & 3) * 128; if (c0 > 308) c0 = 308; }
  else if (b < 5688)   { b -= 3952; q = 1; ef = ef_e; efb = out + OFF_EFE;
                         pr = b / 7;  c0 = (b - pr * 7) * 64; if (c0 > 371) c0 = 371; }
  else                 { b -= 5688; q = 3; ef = ef_w; efb = out + OFF_EFW;
                         pr = b / 7;  c0 = (b - pr * 7) * 64; if (c0 > 371) c0 = 371; }
  const float* xqq = xq + (size_t)q * NN * 32;

  // ---- per-thread staging bases for the 3 K-chunks
  const int srow = t >> 1, q0 = t & 1;
  const float *base0, *base1, *base2;
  if (q == 0) {                       // north: erow=row; src=e+436, dst=e
    const int e = row * 436 + c0 + srow;
    base0 = ef  + (size_t)e * 32;
    base1 = xqq + (size_t)(e + 436) * 32;
    base2 = xqq + (size_t)e * 32;
  } else if (q == 2) {                // south: src=e, dst=e+436
    const int e = row * 436 + c0 + srow;
    base0 = ef  + (size_t)e * 32;
    base1 = xqq + (size_t)e * 32;
    base2 = xqq + (size_t)(e + 436) * 32;
  } else {
    int r = 2 * pr + (srow >> 6); if (r > 494) r = 494;
    const int cc = c0 + (srow & 63);
    if (q == 1) {                     // east: src=r*436+c, dst=src+1
      base0 = ef  + ((size_t)r * 435 + cc) * 32;
      base1 = xqq + ((size_t)r * 436 + cc) * 32;
      base2 = base1 + 32;
    } else {                          // west: cm=cc, c=cc+1, dst=src-1
      base0 = ef  + ((size_t)r * 435 + cc) * 32;
      base1 = xqq + ((size_t)r * 436 + cc + 1) * 32;
      base2 = base1 - 32;
    }
  }

  // ---- prefetch ALL A data (one latency exposure per block)
  floatx4 pv[3][2][2];
#pragma unroll
  for (int kc = 0; kc < 3; ++kc) {
    const float* src = (kc == 0) ? base0 : (kc == 1) ? base1 : base2;
#pragma unroll
    for (int cc = 0; cc < 2; ++cc) {
      pv[kc][cc][0] = *(const floatx4*)(src + (q0 + 2 * cc) * 8);
      pv[kc][cc][1] = *(const floatx4*)(src + (q0 + 2 * cc) * 8 + 4);
    }
  }
  // ---- stage B once: 768 16B-slabs across hi+lo planes
#pragma unroll
  for (int r = 0; r < 3; ++r) {
    const int g = r * 256 + t;
    const bool lo = g >= 384;
    const int f = lo ? g - 384 : g;
    const int col = f / 12, rem = f - col * 12, kc = rem >> 2, ch = rem & 3;
    const unsigned short* sp = (lo ? g_wd_l : g_wd_h) +
                               (size_t)(q * 32 + col) * 96 + kc * 32 + ch * 8;
    short* dp = lo ? Bs_l : Bs_h;
    const int off = col * 192 + kc * 64 + ((ch * 16) ^ ((col & 3) << 4));
    *(short8v*)((char*)dp + off) = *(const short8v*)sp;
  }

  const int w = t >> 6, lane = t & 63;
  const int lr = lane & 15, lg = lane >> 4;

  floatx4 acc[2][2];
#pragma unroll
  for (int mi = 0; mi < 2; ++mi)
#pragma unroll
    for (int ni = 0; ni < 2; ++ni) acc[mi][ni] = (floatx4){0.f, 0.f, 0.f, 0.f};

#pragma unroll
  for (int kc = 0; kc < 3; ++kc) {
    bar_lds();                        // WAR on As; (kc=0: orders B stage too)
#pragma unroll
    for (int cc = 0; cc < 2; ++cc) {
      const int qch = q0 + 2 * cc;
      short8v hv, lv;
#pragma unroll
      for (int j = 0; j < 4; ++j) {
        unsigned short h, l;
        bf16split(pv[kc][cc][0][j], h, l); hv[j] = (short)h; lv[j] = (short)l;
        bf16split(pv[kc][cc][1][j], h, l); hv[4 + j] = (short)h; lv[4 + j] = (short)l;
      }
      const int off = srow * 64 + ((qch * 16) ^ ((srow & 3) << 4));
      *(short8v*)((char*)As_h + off) = hv;
      *(short8v*)((char*)As_l + off) = lv;
    }
    bar_lds();
    short8v ah[2], al[2], bh[2], bl[2];
#pragma unroll
    for (int mi = 0; mi < 2; ++mi) {
      const int rowm = 64 * mi + 16 * w + lr;
      const int off = rowm * 64 + ((lg * 16) ^ ((rowm & 3) << 4));
      ah[mi] = *(const short8v*)((const char*)As_h + off);
      al[mi] = *(const short8v*)((const char*)As_l + off);
    }
#pragma unroll
    for (int ni = 0; ni < 2; ++ni) {
      const int col = 16 * ni + lr;
      const int off = col * 192 + kc * 64 + ((lg * 16) ^ ((col & 3) << 4));
      bh[ni] = *(const short8v*)((const char*)Bs_h + off);
      bl[ni] = *(const short8v*)((const char*)Bs_l + off);
    }
#pragma unroll
    for (int ni = 0; ni < 2; ++ni)
#pragma unroll
      for (int mi = 0; mi < 2; ++mi) {
        acc[mi][ni] = __builtin_amdgcn_mfma_f32_16x16x32_bf16(ah[mi], bh[ni], acc[mi][ni], 0, 0, 0);
        acc[mi][ni] = __builtin_amdgcn_mfma_f32_16x16x32_bf16(ah[mi], bl[ni], acc[mi][ni], 0, 0, 0);
        acc[mi][ni] = __builtin_amdgcn_mfma_f32_16x16x32_bf16(al[mi], bh[ni], acc[mi][ni], 0, 0, 0);
      }
  }

  // ---- epilogue: relu; agg scatter; pooled-max efeat
  float vv[2][2][4];
#pragma unroll
  for (int mi = 0; mi < 2; ++mi)
#pragma unroll
    for (int ni = 0; ni < 2; ++ni)
#pragma unroll
      for (int r = 0; r < 4; ++r) vv[mi][ni][r] = fmaxf(acc[mi][ni][r], 0.f);

#pragma unroll
  for (int ni = 0; ni < 2; ++ni) {
    const int colo = q * 32 + 16 * ni + lr;
#pragma unroll
    for (int mi = 0; mi < 2; ++mi) {
      size_t dstb;
      if (q == 0)      dstb = (size_t)row * 436 + c0 + 64 * mi + 16 * w + 4 * lg;
      else if (q == 2) dstb = (size_t)(row + 1) * 436 + c0 + 64 * mi + 16 * w + 4 * lg;
      else {
        int r2 = 2 * pr + mi; if (r2 > 494) r2 = 494;
        dstb = (size_t)r2 * 436 + c0 + 16 * w + 4 * lg + (q == 1 ? 1 : 0);
      }
#pragma unroll
      for (int r = 0; r < 4; ++r)
        agg[(dstb + r) * 128 + colo] = vv[mi][ni][r] * 0.25f;
    }
  }

  if (q == 0 || q == 2) {
    if (row & 1) {                    // kept rows: north erow odd, south r odd
      const int krow = row >> 1;
#pragma unroll
      for (int ni = 0; ni < 2; ++ni)
#pragma unroll
        for (int mi = 0; mi < 2; ++mi)
#pragma unroll
          for (int k = 0; k < 2; ++k) {
            const int c = c0 + 64 * mi + 16 * w + 4 * lg + 2 * k;
            const int kidx = krow * 218 + (c >> 1);
            const float val = fmaxf(vv[mi][ni][2 * k], vv[mi][ni][2 * k + 1]);
            efb[(size_t)kidx * 32 + 16 * ni + lr] = val;
          }
    }
  } else {
#pragma unroll
    for (int ni = 0; ni < 2; ++ni)
#pragma unroll
      for (int r = 0; r < 4; ++r) {
        const int jj = 16 * w + 4 * lg + r;
        const int c = c0 + jj + (q == 3 ? 1 : 0);
        const bool kept = (q == 1) ? ((c & 1) == 1) : ((c & 1) == 0);
        if (kept) {
          const int kidx = pr * 217 + (c >> 1) - (q == 3 ? 1 : 0);
          const float val = fmaxf(vv[0][ni][r], vv[1][ni][r]);
          efb[(size_t)kidx * 32 + 16 * ni + lr] = val;
        }
      }
  }
}

// ---------------------------------------------------------------------------
// Kernel D: zero agg boundary strips + closed-form new_pos + pooled edge
// indices + W_node / W_emb / W_edge transpose-split prep.
__global__ __launch_bounds__(256) void k_misc(float* __restrict__ out,
                                              float* __restrict__ agg,
                                              const float* __restrict__ W_node,
                                              const float* __restrict__ W_emb,
                                              const float* __restrict__ W_edge) {
  int u = blockIdx.x * 256 + threadIdx.x;
  if (u < 436 * 32) {  // north: dst row 494 missing
    agg[((size_t)494 * 436 + (u >> 5)) * 128 + (u & 31)] = 0.f; return;
  }
  u -= 436 * 32;
  if (u < 495 * 32) {  // east: dst col 0 missing
    agg[(size_t)(u >> 5) * 436 * 128 + 32 + (u & 31)] = 0.f; return;
  }
  u -= 495 * 32;
  if (u < 436 * 32) {  // south: dst row 0 missing
    agg[(size_t)(u >> 5) * 128 + 64 + (u & 31)] = 0.f; return;
  }
  u -= 436 * 32;
  if (u < 495 * 32) {  // west: dst col 435 missing
    agg[((size_t)(u >> 5) * 436 + 435) * 128 + 96 + (u & 31)] = 0.f; return;
  }
  u -= 495 * 32;
  if (u < NPOOL * 2) {
    const int p  = u >> 1;
    const int pr = p / 218, pc = p - pr * 218;
    out[OFF_POS + u] = (float)((u & 1) ? pc : pr); return;
  }
  u -= NPOOL * 2;
  if (u < KN * 2) {   // north
    const int e  = u >> 1;
    const int kr = e / 218 + 1, pc = e - (kr - 1) * 218;
    const int s  = kr * 218 + pc;
    out[OFF_EIN + u] = (float)((u & 1) ? (s - 218) : s); return;
  }
  u -= KN * 2;
  if (u < KE * 2) {   // east
    const int e  = u >> 1;
    const int pr = e / 217, jj = e - pr * 217;
    const int s  = pr * 218 + jj;
    out[OFF_EIE + u] = (float)((u & 1) ? (s + 1) : s); return;
  }
  u -= KE * 2;
  if (u < KN * 2) {   // south
    const int e  = u >> 1;
    const int k  = e / 218, pc = e - k * 218;
    const int s  = k * 218 + pc;
    out[OFF_EIS + u] = (float)((u & 1) ? (s + 218) : s); return;
  }
  u -= KN * 2;
  if (u < KE * 2) {   // west
    const int e  = u >> 1;
    const int pr = e / 217, jj = e - pr * 217;
    const int s  = pr * 218 + jj + 1;
    out[OFF_EIW + u] = (float)((u & 1) ? (s - 1) : s); return;
  }
  u -= KE * 2;
  if (u < 256 * 128) { // W_node [k][c] -> transposed bf16 hi/lo planes [c][k]
    const int k = u >> 7, c = u & 127;
    unsigned short h, l;
    bf16split(W_node[u], h, l);
    g_wn_h[(size_t)c * 256 + k] = h;
    g_wn_l[(size_t)c * 256 + k] = l;
    return;
  }
  u -= 256 * 128;
  if (u < 4 * 128 * 32) { // W_emb [q][k][uu] -> planes [(q*32+uu)][k]
    const int q = u >> 12, k = (u >> 5) & 127, uu = u & 31;
    unsigned short h, l;
    bf16split(W_emb[u], h, l);
    g_we_h[(size_t)(q * 32 + uu) * 128 + k] = h;
    g_we_l[(size_t)(q * 32 + uu) * 128 + k] = l;
    return;
  }
  u -= 4 * 128 * 32;
  if (u < 4 * 96 * 32) { // W_edge [q][k][col] -> planes [(q*32+col)][k 0..95]
    const int q = u / 3072, rem = u - q * 3072;
    const int k = rem >> 5, col = rem & 31;
    unsigned short h, l;
    bf16split(W_edge[u], h, l);
    g_wd_h[(size_t)(q * 32 + col) * 96 + k] = h;
    g_wd_l[(size_t)(q * 32 + col) * 96 + k] = l;
  }
}

// ---------------------------------------------------------------------------
extern "C" void kernel_launch(void* const* d_in, const int* in_sizes, int n_in,
                              void* d_out, int out_size, void* d_ws, size_t ws_size,
                              hipStream_t stream) {
  const float* x      = (const float*)d_in[0];
  const float* ef_n   = (const float*)d_in[6];
  const float* ef_e   = (const float*)d_in[7];
  const float* ef_s   = (const float*)d_in[8];
  const float* ef_w   = (const float*)d_in[9];
  const float* W_emb  = (const float*)d_in[10];
  const float* W_edge = (const float*)d_in[11];
  const float* W_node = (const float*)d_in[12];
  float* out = (float*)d_out;

  float* xq  = (float*)d_ws;                 // [4][NN][32]
  float* agg = xq + (size_t)NN * 128;        // [NN][128]

  const int misc_total = (436 + 495 + 436 + 495) * 32 + NPOOL * 2 +
                         2 * (KN * 2 + KE * 2) + 256 * 128 + 4 * 128 * 32 +
                         4 * 96 * 32;
  k_misc<<<dim3((misc_total + 255) / 256), 256, 0, stream>>>(out, agg, W_node,
                                                             W_emb, W_edge);
  k_xq  <<<dim3((NN + 127) / 128), 256, 0, stream>>>(x, xq);
  k_edge<<<dim3(7424), 256, 0, stream>>>(ef_n, ef_e, ef_s, ef_w,
                                         xq, agg, out);
  k_node<<<dim3(7, 248), 256, 0, stream>>>(x, agg, out);
}